// Round 9
// baseline (496.197 us; speedup 1.0000x reference)
//
#include <hip/hip_runtime.h>
#include <cstdint>
#include <cstddef>

#define B 8
#define C 192
#define H 128
#define W 128
#define HW (H * W)
#define CHW ((size_t)C * HW)
#define K C                    // GEMM K dim = 192

typedef __attribute__((ext_vector_type(8))) short short8v;
typedef __attribute__((ext_vector_type(4))) float f32x4;
typedef __attribute__((ext_vector_type(4))) unsigned short ushort4v;

__device__ __forceinline__ float bf2f(unsigned short s) {
    union { float f; unsigned u; } cv; cv.u = ((unsigned)s) << 16; return cv.f;
}
__device__ __forceinline__ unsigned short f2bf(float f) {
    union { float f; unsigned u; } cv; cv.f = f;
    unsigned r = (cv.u + 0x7fffu + ((cv.u >> 16) & 1u)) >> 16;
    return (unsigned short)r;
}

// ---------------- weight prepack fp32 -> bf16 (par | loc | out) ----------------
__global__ void prepack_kernel(const float* __restrict__ pw, const float* __restrict__ lw,
                               const float* __restrict__ ow, unsigned short* __restrict__ wb) {
    int i = blockIdx.x * 256 + threadIdx.x;
    const int NPW = 3 * C * K, NL = C * K;
    if (i < NPW) wb[i] = f2bf(pw[i]);
    else if (i < NPW + NL) wb[i] = f2bf(lw[i - NPW]);
    else if (i < NPW + 2 * NL) wb[i] = f2bf(ow[i - NPW - NL]);
}

// ---------------- LayerNorm over C -> z_t [p][K] bf16 ----------------
__global__ void ln_kernel(const float* __restrict__ x, const float* __restrict__ lw,
                          const float* __restrict__ lb, unsigned short* __restrict__ zt) {
    int p = blockIdx.x * 256 + threadIdx.x;   // [0, nb*HW)
    int b = p >> 14, hw = p & 16383;
    const float* xp = x + (size_t)b * CHW + hw;
    float sum = 0.f, sq = 0.f;
    for (int c = 0; c < C; ++c) {
        float v = xp[(size_t)c * HW];
        sum += v; sq += v * v;
    }
    float mean = sum * (1.0f / C);
    float var = fmaxf(sq * (1.0f / C) - mean * mean, 0.f);
    float rs = rsqrtf(var + 1e-6f);
    unsigned short* zp = zt + (size_t)p * K;
#pragma unroll 4
    for (int c8 = 0; c8 < K / 8; ++c8) {
        short8v v;
#pragma unroll
        for (int j = 0; j < 8; ++j) {
            int c = c8 * 8 + j;
            float r = (xp[(size_t)c * HW] - mean) * rs * lw[c] + lb[c];
            v[j] = (short)f2bf(r);
        }
        *(short8v*)(zp + c8 * 8) = v;
    }
}

// ---------------- MFMA 1x1 conv, LDS-staged weights, D[p][o] orientation --------
// MODE 0: gates — gy loop 0..2 inside (sigmoid; 0->A, 1->U(*=z), 2->G; bf16 NCHW)
// MODE 1: +bias -> Pb16 (bf16 NCHW)
// MODE 2: input = yin bf16 NCHW; +bias +xres -> Pf (fp32 NCHW)
template <int MODE>
__global__ __launch_bounds__(256, 2)
void conv_mfma_kernel(const unsigned short* __restrict__ zt, const unsigned short* __restrict__ yin,
                      const unsigned short* __restrict__ wb, const float* __restrict__ bias,
                      const float* __restrict__ xres, float* __restrict__ Pf,
                      unsigned short* __restrict__ PA, unsigned short* __restrict__ PU,
                      unsigned short* __restrict__ PG) {
    extern __shared__ char smem[];               // 73728 B weight tile
    int tid = threadIdx.x;
    int lane = tid & 63, wv = tid >> 6;
    int p0 = blockIdx.x * 256 + wv * 64;         // wave's 64 pixels
    int lr = lane & 15, lh = lane >> 4;
    int sw = (lr & 7) << 4;

    // B-fragments: pixel rows (lr), k-chunk lh*8 — loaded ONCE
    short8v bfr[4][6];
    if (MODE != 2) {
#pragma unroll
        for (int s = 0; s < 4; ++s) {
            const unsigned short* zr = zt + (size_t)(p0 + s * 16 + lr) * K + lh * 8;
#pragma unroll
            for (int t = 0; t < 6; ++t) bfr[s][t] = *(const short8v*)(zr + t * 32);
        }
    } else {
        int bl = p0 >> 14, hwb = p0 & 16383;
        const unsigned short* yb = yin + (size_t)bl * CHW;
#pragma unroll
        for (int s = 0; s < 4; ++s) {
            int hw = hwb + s * 16 + lr;
#pragma unroll
            for (int t = 0; t < 6; ++t) {
                int c0 = t * 32 + lh * 8;
                short8v v;
#pragma unroll
                for (int j = 0; j < 8; ++j)
                    v[j] = (short)yb[(size_t)(c0 + j) * HW + hw];
                bfr[s][t] = v;
            }
        }
    }

    const int NGY = (MODE == 0) ? 3 : 1;
    for (int gy = 0; gy < NGY; ++gy) {
        if (gy) __syncthreads();                 // prior compute done before restage
        const unsigned short* wsrc = wb + (size_t)gy * C * K;
#pragma unroll
        for (int it = 0; it < 18; ++it) {
            int e8 = it * 256 + tid;
            int row = e8 / 24;
            int cb = (e8 % 24) * 16;
            short8v v = *(const short8v*)(wsrc + e8 * 8);
            *(short8v*)(smem + row * 384 + (cb ^ ((row & 7) << 4))) = v;
        }
        __syncthreads();

        for (int ot = 0; ot < 12; ++ot) {
            int row = ot * 16 + lr;              // output channel this lane owns
            int rb = row * 384;
            f32x4 acc[4];
#pragma unroll
            for (int s = 0; s < 4; ++s) acc[s] = (f32x4){0.f, 0.f, 0.f, 0.f};
#pragma unroll
            for (int t = 0; t < 6; ++t) {
                short8v af = *(const short8v*)(smem + rb + ((t * 64 + lh * 16) ^ sw));
#pragma unroll
                for (int s = 0; s < 4; ++s)
                    acc[s] = __builtin_amdgcn_mfma_f32_16x16x32_bf16(bfr[s][t], af, acc[s], 0, 0, 0);
            }
            int o = row;
            float bi = bias[(MODE == 0 ? gy * C : 0) + o];
#pragma unroll
            for (int s = 0; s < 4; ++s) {
                int pst = p0 + s * 16 + lh * 4;
                int bl = pst >> 14, hw = pst & 16383;
                if (MODE == 0) {
                    ushort4v q;
#pragma unroll
                    for (int j = 0; j < 4; ++j) {
                        float v = acc[s][j] + bi;
                        v = 1.f / (1.f + __expf(-v));
                        if (gy == 1) v *= bf2f(zt[(size_t)(pst + j) * K + o]);
                        q[j] = f2bf(v);
                    }
                    unsigned short* dst = (gy == 0) ? PA : ((gy == 1) ? PU : PG);
                    *(ushort4v*)(dst + (size_t)bl * CHW + (size_t)o * HW + hw) = q;
                } else if (MODE == 1) {
                    ushort4v q;
#pragma unroll
                    for (int j = 0; j < 4; ++j) q[j] = f2bf(acc[s][j] + bi);
                    *(ushort4v*)(PA + (size_t)bl * CHW + (size_t)o * HW + hw) = q;
                } else {
                    size_t ad = (size_t)bl * CHW + (size_t)o * HW + hw;
                    f32x4 x4 = *(const f32x4*)(xres + ad);
                    f32x4 q;
#pragma unroll
                    for (int j = 0; j < 4; ++j) q[j] = acc[s][j] + bi + x4[j];
                    *(f32x4*)(Pf + ad) = q;
                }
            }
        }
    }
}

// ------- 3x3 depthwise conv on z_t -> d_t [p][K] bf16 (XCD-swizzled, c8-split) -------
// grid: (nb*64 pixel-tiles, 6 channel-groups); tile = 256 pixels (2 image rows)
__global__ __launch_bounds__(256)
void dw3x3_kernel(const unsigned short* __restrict__ zt, const float* __restrict__ wgt,
                  unsigned short* __restrict__ dt) {
    // XCD-chunked bijective swizzle (gridDim.x = nb*64, divisible by 8):
    // all vertical-neighbor tiles + all 6 c8-groups of a tile land on one XCD's L2.
    int tl = (blockIdx.x & 7) * (gridDim.x >> 3) + (blockIdx.x >> 3);
    int p = tl * 256 + threadIdx.x;
    int hw = p & 16383, h = hw >> 7, w = hw & 127;
#pragma unroll
    for (int cc = 0; cc < 4; ++cc) {
        int c8 = blockIdx.y * 4 + cc;
        float kw[8][9];
#pragma unroll
        for (int j = 0; j < 8; ++j)
#pragma unroll
            for (int t = 0; t < 9; ++t) kw[j][t] = wgt[(c8 * 8 + j) * 9 + t];
        float acc[8];
#pragma unroll
        for (int j = 0; j < 8; ++j) acc[j] = 0.f;
#pragma unroll
        for (int dy = -1; dy <= 1; ++dy) {
            if (h + dy < 0 || h + dy >= H) continue;
#pragma unroll
            for (int dx = -1; dx <= 1; ++dx) {
                if (w + dx < 0 || w + dx >= W) continue;
                short8v zv = *(const short8v*)(zt + (size_t)(p + dy * W + dx) * K + c8 * 8);
                int t = (dy + 1) * 3 + (dx + 1);
#pragma unroll
                for (int j = 0; j < 8; ++j) acc[j] += kw[j][t] * bf2f((unsigned short)zv[j]);
            }
        }
        short8v ov;
#pragma unroll
        for (int j = 0; j < 8; ++j) ov[j] = (short)f2bf(acc[j]);
        *(short8v*)(dt + (size_t)p * K + c8 * 8) = ov;
    }
}

// ------ fused scans: W-scan + chunked H-scan + loc add + silu, in-place bf16 ------
// block = 1024 threads per (b,c) plane; LY (bf16 NCHW) read: loc conv out, write: Y
__global__ __launch_bounds__(1024)
void scan_fused_kernel(const unsigned short* __restrict__ A_, const unsigned short* __restrict__ U_,
                       const unsigned short* __restrict__ G_, unsigned short* __restrict__ LY) {
    extern __shared__ float Sl[];                // [HW] raw w-scan sums (no g)
    float* AF = Sl + HW;                         // [8][128]
    float* UF = AF + 1024;                       // [8][128] -> fwd exclusive prefix
    float* AB = UF + 1024;                       // [8][128]
    float* UB = AB + 1024;                       // [8][128] -> bwd exclusive prefix
    int tid = threadIdx.x, lane = tid & 63, wvi = tid >> 6;
    size_t pb = (size_t)blockIdx.x * HW;

    // ---- phase 0: W-scan, wave wvi owns rows wvi*8..+7; store s_f+s_b (no g) ----
#pragma unroll
    for (int i = 0; i < 8; ++i) {
        int r = wvi * 8 + i;
        size_t base = pb + (size_t)r * W;
        ushort2 av = *(const ushort2*)(A_ + base + 2 * lane);
        ushort2 uv = *(const ushort2*)(U_ + base + 2 * lane);
        float a0 = bf2f(av.x), a1 = bf2f(av.y);
        float u0 = bf2f(uv.x), u1 = bf2f(uv.y);

        float Aa = a0 * a1;
        float Uu = a1 * u0 + u1;
#pragma unroll
        for (int d = 1; d < 64; d <<= 1) {
            float Ao = __shfl_up(Aa, (unsigned)d, 64);
            float Uo = __shfl_up(Uu, (unsigned)d, 64);
            if (lane >= d) { Uu = Aa * Uo + Uu; Aa = Aa * Ao; }
        }
        float sp = __shfl_up(Uu, 1u, 64);
        if (lane == 0) sp = 0.f;
        float s0 = a0 * sp + u0;
        float s1 = a1 * s0 + u1;

        Aa = a0 * a1;
        Uu = a0 * u1 + u0;
#pragma unroll
        for (int d = 1; d < 64; d <<= 1) {
            float Ao = __shfl_down(Aa, (unsigned)d, 64);
            float Uo = __shfl_down(Uu, (unsigned)d, 64);
            if (lane + d < 64) { Uu = Aa * Uo + Uu; Aa = Aa * Ao; }
        }
        float tn = __shfl_down(Uu, 1u, 64);
        if (lane == 63) tn = 0.f;
        float t1 = a1 * tn + u1;
        float t0 = a0 * t1 + u0;

        Sl[r * W + 2 * lane]     = s0 + t0;
        Sl[r * W + 2 * lane + 1] = s1 + t1;
    }

    // ---- phase 1a: per-thread chunk compose (w = tid&127, 16 rows per chunk) ----
    int w = tid & 127, ck = tid >> 7;            // ck 0..7
    int h0 = ck * 16;
    float av[16], uv[16];
#pragma unroll
    for (int i = 0; i < 16; ++i) {
        size_t off = pb + (size_t)(h0 + i) * W + w;
        av[i] = bf2f(A_[off]);
        uv[i] = bf2f(U_[off]);
    }
    float Af = 1.f, Uf = 0.f, Ab = 1.f, Ub = 0.f;
#pragma unroll
    for (int i = 0; i < 16; ++i) { Uf = av[i] * Uf + uv[i]; Af *= av[i]; }
#pragma unroll
    for (int i = 15; i >= 0; --i) { Ub = av[i] * Ub + uv[i]; Ab *= av[i]; }
    AF[ck * 128 + w] = Af; UF[ck * 128 + w] = Uf;
    AB[ck * 128 + w] = Ab; UB[ck * 128 + w] = Ub;
    __syncthreads();

    // ---- phase 1b: serial scan over 8 chunks per column (exclusive prefix) ----
    if (tid < 128) {
        float s = 0.f;
#pragma unroll
        for (int k = 0; k < 8; ++k) {
            float Aa = AF[k * 128 + tid], Uu = UF[k * 128 + tid];
            UF[k * 128 + tid] = s;
            s = Aa * s + Uu;
        }
    } else if (tid < 256) {
        int ww = tid - 128;
        float s = 0.f;
#pragma unroll
        for (int k = 7; k >= 0; --k) {
            float Aa = AB[k * 128 + ww], Uu = UB[k * 128 + ww];
            UB[k * 128 + ww] = s;
            s = Aa * s + Uu;
        }
    }
    __syncthreads();

    // ---- phase 1c: apply prefixes; y = silu(loc + 0.5*g*(wsum + hsum)); in place ----
    float sf = UF[ck * 128 + w];
    float sfa[16];
#pragma unroll
    for (int i = 0; i < 16; ++i) { sf = av[i] * sf + uv[i]; sfa[i] = sf; }
    float sb = UB[ck * 128 + w];
#pragma unroll
    for (int i = 15; i >= 0; --i) {
        sb = av[i] * sb + uv[i];
        size_t off = pb + (size_t)(h0 + i) * W + w;
        float g = bf2f(G_[off]);
        float v = bf2f(LY[off]) + 0.5f * g * (Sl[(h0 + i) * W + w] + sfa[i] + sb);
        LY[off] = f2bf(v / (1.f + __expf(-v)));
    }
}

extern "C" void kernel_launch(void* const* d_in, const int* in_sizes, int n_in,
                              void* d_out, int out_size, void* d_ws, size_t ws_size,
                              hipStream_t stream) {
    const float* x     = (const float*)d_in[0];
    const float* ln_w  = (const float*)d_in[1];
    const float* ln_b  = (const float*)d_in[2];
    const float* dw_w  = (const float*)d_in[3];
    const float* loc_w = (const float*)d_in[4];
    const float* loc_b = (const float*)d_in[5];
    const float* par_w = (const float*)d_in[6];
    const float* par_b = (const float*)d_in[7];
    const float* out_w = (const float*)d_in[8];
    const float* out_b = (const float*)d_in[9];
    float* out = (float*)d_out;
    unsigned short* wsu = (unsigned short*)d_ws;

    // ws (bf16 units): WB(184320) | A | U | G | ZT(->LOC->Y) | DT, each nb*CHW
    const int WBN = 5 * C * K;                 // 184320
    int nb = 8;
    while (nb > 1) {
        size_t need = (size_t)WBN * 2 + (size_t)5 * nb * CHW * 2;
        if (need <= ws_size) break;
        nb >>= 1;
    }

    prepack_kernel<<<(WBN + 255) / 256, 256, 0, stream>>>(par_w, loc_w, out_w, wsu);

    for (int b0 = 0; b0 < B; b0 += nb) {
        size_t ge = (size_t)nb * CHW;
        unsigned short* WB = wsu;
        unsigned short* Ab = wsu + WBN;
        unsigned short* Ub = Ab + ge;
        unsigned short* Gb = Ub + ge;
        unsigned short* ZT = Gb + ge;          // LN out; later LOC (bf16 NCHW), then Y
        unsigned short* DT = ZT + ge;
        const float* xg = x + (size_t)b0 * CHW;
        int npg = nb * HW;

        // 1. LayerNorm -> ZT [p][K]
        ln_kernel<<<npg / 256, 256, 0, stream>>>(xg, ln_w, ln_b, ZT);
        // 2. gates (3 gy in one kernel) -> A, U, G (bf16 NCHW)
        conv_mfma_kernel<0><<<npg / 256, 256, 73728, stream>>>(
            ZT, nullptr, WB, par_b, nullptr, nullptr, Ab, Ub, Gb);
        // 3. depthwise 3x3 -> DT [p][K]  (XCD-swizzled, 6 channel-groups)
        dw3x3_kernel<<<dim3(npg / 256, 6), 256, 0, stream>>>(ZT, dw_w, DT);
        // 4. local conv -> LOC (bf16 NCHW) overwriting ZT (now dead)
        conv_mfma_kernel<1><<<npg / 256, 256, 73728, stream>>>(
            DT, nullptr, WB + 3 * C * K, loc_b, nullptr, nullptr, ZT, nullptr, nullptr);
        // 5. fused scans + loc add + silu, in place -> Y (= ZT buffer)
        scan_fused_kernel<<<nb * C, 1024, (HW + 4096) * 4, stream>>>(Ab, Ub, Gb, ZT);
        // 6. out conv (reads Y bf16) + bias + residual -> d_out
        conv_mfma_kernel<2><<<npg / 256, 256, 73728, stream>>>(
            nullptr, ZT, WB + 4 * C * K, out_b, xg, out + (size_t)b0 * CHW,
            nullptr, nullptr, nullptr);
    }
}

// Round 10
// 382.753 us; speedup vs baseline: 1.2964x; 1.2964x over previous
//
#include <hip/hip_runtime.h>
#include <cstdint>
#include <cstddef>

#define B 8
#define C 192
#define H 128
#define W 128
#define HW (H * W)
#define CHW ((size_t)C * HW)
#define K C                    // GEMM K dim = 192

typedef __attribute__((ext_vector_type(8))) short short8v;
typedef __attribute__((ext_vector_type(4))) float f32x4;
typedef __attribute__((ext_vector_type(4))) unsigned short ushort4v;

__device__ __forceinline__ float bf2f(unsigned short s) {
    union { float f; unsigned u; } cv; cv.u = ((unsigned)s) << 16; return cv.f;
}
__device__ __forceinline__ unsigned short f2bf(float f) {
    union { float f; unsigned u; } cv; cv.f = f;
    unsigned r = (cv.u + 0x7fffu + ((cv.u >> 16) & 1u)) >> 16;
    return (unsigned short)r;
}

// ---------------- weight prepack fp32 -> bf16 (par | loc | out) ----------------
__global__ void prepack_kernel(const float* __restrict__ pw, const float* __restrict__ lw,
                               const float* __restrict__ ow, unsigned short* __restrict__ wb) {
    int i = blockIdx.x * 256 + threadIdx.x;
    const int NPW = 3 * C * K, NL = C * K;
    if (i < NPW) wb[i] = f2bf(pw[i]);
    else if (i < NPW + NL) wb[i] = f2bf(lw[i - NPW]);
    else if (i < NPW + 2 * NL) wb[i] = f2bf(ow[i - NPW - NL]);
}

// ---------------- LayerNorm over C -> z_t [p][K] bf16 ----------------
__global__ void ln_kernel(const float* __restrict__ x, const float* __restrict__ lw,
                          const float* __restrict__ lb, unsigned short* __restrict__ zt) {
    int p = blockIdx.x * 256 + threadIdx.x;   // [0, nb*HW)
    int b = p >> 14, hw = p & 16383;
    const float* xp = x + (size_t)b * CHW + hw;
    float sum = 0.f, sq = 0.f;
    for (int c = 0; c < C; ++c) {
        float v = xp[(size_t)c * HW];
        sum += v; sq += v * v;
    }
    float mean = sum * (1.0f / C);
    float var = fmaxf(sq * (1.0f / C) - mean * mean, 0.f);
    float rs = rsqrtf(var + 1e-6f);
    unsigned short* zp = zt + (size_t)p * K;
#pragma unroll 4
    for (int c8 = 0; c8 < K / 8; ++c8) {
        short8v v;
#pragma unroll
        for (int j = 0; j < 8; ++j) {
            int c = c8 * 8 + j;
            float r = (xp[(size_t)c * HW] - mean) * rs * lw[c] + lb[c];
            v[j] = (short)f2bf(r);
        }
        *(short8v*)(zp + c8 * 8) = v;
    }
}

// ---------------- MFMA 1x1 conv, LDS-staged weights, D[p][o] orientation --------
// MODE 0: gates — gy loop 0..2 inside (sigmoid; 0->A, 1->U(*=z), 2->G; bf16 NCHW)
// MODE 1: +bias -> Pb16 (bf16 NCHW)
// MODE 2: input = yin bf16 NCHW; +bias +xres -> Pf (fp32 NCHW)
template <int MODE>
__global__ __launch_bounds__(256, 2)
void conv_mfma_kernel(const unsigned short* __restrict__ zt, const unsigned short* __restrict__ yin,
                      const unsigned short* __restrict__ wb, const float* __restrict__ bias,
                      const float* __restrict__ xres, float* __restrict__ Pf,
                      unsigned short* __restrict__ PA, unsigned short* __restrict__ PU,
                      unsigned short* __restrict__ PG) {
    extern __shared__ char smem[];               // 73728 B weight tile
    int tid = threadIdx.x;
    int lane = tid & 63, wv = tid >> 6;
    int p0 = blockIdx.x * 256 + wv * 64;         // wave's 64 pixels
    int lr = lane & 15, lh = lane >> 4;
    int sw = (lr & 7) << 4;

    // B-fragments: pixel rows (lr), k-chunk lh*8 — loaded ONCE
    short8v bfr[4][6];
    if (MODE != 2) {
#pragma unroll
        for (int s = 0; s < 4; ++s) {
            const unsigned short* zr = zt + (size_t)(p0 + s * 16 + lr) * K + lh * 8;
#pragma unroll
            for (int t = 0; t < 6; ++t) bfr[s][t] = *(const short8v*)(zr + t * 32);
        }
    } else {
        int bl = p0 >> 14, hwb = p0 & 16383;
        const unsigned short* yb = yin + (size_t)bl * CHW;
#pragma unroll
        for (int s = 0; s < 4; ++s) {
            int hw = hwb + s * 16 + lr;
#pragma unroll
            for (int t = 0; t < 6; ++t) {
                int c0 = t * 32 + lh * 8;
                short8v v;
#pragma unroll
                for (int j = 0; j < 8; ++j)
                    v[j] = (short)yb[(size_t)(c0 + j) * HW + hw];
                bfr[s][t] = v;
            }
        }
    }

    const int NGY = (MODE == 0) ? 3 : 1;
    for (int gy = 0; gy < NGY; ++gy) {
        if (gy) __syncthreads();                 // prior compute done before restage
        const unsigned short* wsrc = wb + (size_t)gy * C * K;
#pragma unroll
        for (int it = 0; it < 18; ++it) {
            int e8 = it * 256 + tid;
            int row = e8 / 24;
            int cb = (e8 % 24) * 16;
            short8v v = *(const short8v*)(wsrc + e8 * 8);
            *(short8v*)(smem + row * 384 + (cb ^ ((row & 7) << 4))) = v;
        }
        __syncthreads();

        for (int ot = 0; ot < 12; ++ot) {
            int row = ot * 16 + lr;              // output channel this lane owns
            int rb = row * 384;
            f32x4 acc[4];
#pragma unroll
            for (int s = 0; s < 4; ++s) acc[s] = (f32x4){0.f, 0.f, 0.f, 0.f};
#pragma unroll
            for (int t = 0; t < 6; ++t) {
                short8v af = *(const short8v*)(smem + rb + ((t * 64 + lh * 16) ^ sw));
#pragma unroll
                for (int s = 0; s < 4; ++s)
                    acc[s] = __builtin_amdgcn_mfma_f32_16x16x32_bf16(bfr[s][t], af, acc[s], 0, 0, 0);
            }
            int o = row;
            float bi = bias[(MODE == 0 ? gy * C : 0) + o];
#pragma unroll
            for (int s = 0; s < 4; ++s) {
                int pst = p0 + s * 16 + lh * 4;
                int bl = pst >> 14, hw = pst & 16383;
                if (MODE == 0) {
                    ushort4v q;
#pragma unroll
                    for (int j = 0; j < 4; ++j) {
                        float v = acc[s][j] + bi;
                        v = 1.f / (1.f + __expf(-v));
                        if (gy == 1) v *= bf2f(zt[(size_t)(pst + j) * K + o]);
                        q[j] = f2bf(v);
                    }
                    unsigned short* dst = (gy == 0) ? PA : ((gy == 1) ? PU : PG);
                    *(ushort4v*)(dst + (size_t)bl * CHW + (size_t)o * HW + hw) = q;
                } else if (MODE == 1) {
                    ushort4v q;
#pragma unroll
                    for (int j = 0; j < 4; ++j) q[j] = f2bf(acc[s][j] + bi);
                    *(ushort4v*)(PA + (size_t)bl * CHW + (size_t)o * HW + hw) = q;
                } else {
                    size_t ad = (size_t)bl * CHW + (size_t)o * HW + hw;
                    f32x4 x4 = *(const f32x4*)(xres + ad);
                    f32x4 q;
#pragma unroll
                    for (int j = 0; j < 4; ++j) q[j] = acc[s][j] + bi + x4[j];
                    *(f32x4*)(Pf + ad) = q;
                }
            }
        }
    }
}

// ------- 3x3 depthwise conv, LDS-tiled: block = 8h x 16w pixels, all 192 ch -------
// Stages 10x18 halo'd zt rows (full 384B rows) into LDS with 392B padded stride.
#define TROWS 180              // 10*18 staged pixel rows
#define LPAD  392              // padded LDS row stride in bytes
__global__ __launch_bounds__(256, 2)
void dw3x3_kernel(const unsigned short* __restrict__ zt, const float* __restrict__ wgt,
                  unsigned short* __restrict__ dt) {
    __shared__ char lds[TROWS * LPAD];           // 70560 B
    int tid = threadIdx.x;
    int bx = blockIdx.x;
    int bimg = bx >> 7;                          // 128 tiles per image
    int rem = bx & 127;
    int th = rem >> 3, tw = rem & 7;             // 16 x 8 tiles
    int h0 = th * 8, w0 = tw * 16;
    size_t ibase = (size_t)bimg * HW;

    // ---- stage: 180 rows x 24 chunks of 16B, coalesced within each halo row ----
    for (int e = tid; e < TROWS * 24; e += 256) {
        int row = e / 24, ch = e % 24;
        int hh = row / 18, ww = row % 18;
        int h = h0 - 1 + hh, w = w0 - 1 + ww;
        short8v v;
        if (h >= 0 && h < H && w >= 0 && w < W)
            v = *(const short8v*)(zt + (ibase + h * W + w) * K + ch * 8);
        else
            v = (short8v){0, 0, 0, 0, 0, 0, 0, 0};
        *(short8v*)(lds + row * LPAD + ch * 16) = v;
    }
    __syncthreads();

    // ---- compute: thread -> (h_l, w_l, half); 12 c8 chunks each ----
    int w_l = tid & 15, h_l = (tid >> 4) & 7, half = tid >> 7;
    int p_out = (h0 + h_l) * W + (w0 + w_l);
    unsigned short* dp = dt + (ibase + p_out) * K + half * 96;
#pragma unroll
    for (int cc = 0; cc < 12; ++cc) {
        int c8 = half * 12 + cc;
        float acc[8];
#pragma unroll
        for (int j = 0; j < 8; ++j) acc[j] = 0.f;
#pragma unroll
        for (int dy = -1; dy <= 1; ++dy) {
#pragma unroll
            for (int dx = -1; dx <= 1; ++dx) {
                int row = (h_l + 1 + dy) * 18 + (w_l + 1 + dx);
                short8v zv = *(const short8v*)(lds + row * LPAD + c8 * 16);
                int t = (dy + 1) * 3 + (dx + 1);
#pragma unroll
                for (int j = 0; j < 8; ++j)
                    acc[j] += wgt[(c8 * 8 + j) * 9 + t] * bf2f((unsigned short)zv[j]);
            }
        }
        short8v ov;
#pragma unroll
        for (int j = 0; j < 8; ++j) ov[j] = (short)f2bf(acc[j]);
        *(short8v*)(dp + cc * 8) = ov;
    }
}

// ------ fused scans: W-scan + chunked H-scan + loc add + silu, in-place bf16 ------
// block = 1024 threads per (b,c) plane; LY (bf16 NCHW) read: loc conv out, write: Y
__global__ __launch_bounds__(1024)
void scan_fused_kernel(const unsigned short* __restrict__ A_, const unsigned short* __restrict__ U_,
                       const unsigned short* __restrict__ G_, unsigned short* __restrict__ LY) {
    extern __shared__ float Sl[];                // [HW] raw w-scan sums (no g)
    float* AF = Sl + HW;                         // [8][128]
    float* UF = AF + 1024;                       // [8][128] -> fwd exclusive prefix
    float* AB = UF + 1024;                       // [8][128]
    float* UB = AB + 1024;                       // [8][128] -> bwd exclusive prefix
    int tid = threadIdx.x, lane = tid & 63, wvi = tid >> 6;
    size_t pb = (size_t)blockIdx.x * HW;

    // ---- phase 0: W-scan, wave wvi owns rows wvi*8..+7; store s_f+s_b (no g) ----
#pragma unroll
    for (int i = 0; i < 8; ++i) {
        int r = wvi * 8 + i;
        size_t base = pb + (size_t)r * W;
        ushort2 av = *(const ushort2*)(A_ + base + 2 * lane);
        ushort2 uv = *(const ushort2*)(U_ + base + 2 * lane);
        float a0 = bf2f(av.x), a1 = bf2f(av.y);
        float u0 = bf2f(uv.x), u1 = bf2f(uv.y);

        float Aa = a0 * a1;
        float Uu = a1 * u0 + u1;
#pragma unroll
        for (int d = 1; d < 64; d <<= 1) {
            float Ao = __shfl_up(Aa, (unsigned)d, 64);
            float Uo = __shfl_up(Uu, (unsigned)d, 64);
            if (lane >= d) { Uu = Aa * Uo + Uu; Aa = Aa * Ao; }
        }
        float sp = __shfl_up(Uu, 1u, 64);
        if (lane == 0) sp = 0.f;
        float s0 = a0 * sp + u0;
        float s1 = a1 * s0 + u1;

        Aa = a0 * a1;
        Uu = a0 * u1 + u0;
#pragma unroll
        for (int d = 1; d < 64; d <<= 1) {
            float Ao = __shfl_down(Aa, (unsigned)d, 64);
            float Uo = __shfl_down(Uu, (unsigned)d, 64);
            if (lane + d < 64) { Uu = Aa * Uo + Uu; Aa = Aa * Ao; }
        }
        float tn = __shfl_down(Uu, 1u, 64);
        if (lane == 63) tn = 0.f;
        float t1 = a1 * tn + u1;
        float t0 = a0 * t1 + u0;

        Sl[r * W + 2 * lane]     = s0 + t0;
        Sl[r * W + 2 * lane + 1] = s1 + t1;
    }

    // ---- phase 1a: per-thread chunk compose (w = tid&127, 16 rows per chunk) ----
    int w = tid & 127, ck = tid >> 7;            // ck 0..7
    int h0 = ck * 16;
    float av[16], uv[16];
#pragma unroll
    for (int i = 0; i < 16; ++i) {
        size_t off = pb + (size_t)(h0 + i) * W + w;
        av[i] = bf2f(A_[off]);
        uv[i] = bf2f(U_[off]);
    }
    float Af = 1.f, Uf = 0.f, Ab = 1.f, Ub = 0.f;
#pragma unroll
    for (int i = 0; i < 16; ++i) { Uf = av[i] * Uf + uv[i]; Af *= av[i]; }
#pragma unroll
    for (int i = 15; i >= 0; --i) { Ub = av[i] * Ub + uv[i]; Ab *= av[i]; }
    AF[ck * 128 + w] = Af; UF[ck * 128 + w] = Uf;
    AB[ck * 128 + w] = Ab; UB[ck * 128 + w] = Ub;
    __syncthreads();

    // ---- phase 1b: serial scan over 8 chunks per column (exclusive prefix) ----
    if (tid < 128) {
        float s = 0.f;
#pragma unroll
        for (int k = 0; k < 8; ++k) {
            float Aa = AF[k * 128 + tid], Uu = UF[k * 128 + tid];
            UF[k * 128 + tid] = s;
            s = Aa * s + Uu;
        }
    } else if (tid < 256) {
        int ww = tid - 128;
        float s = 0.f;
#pragma unroll
        for (int k = 7; k >= 0; --k) {
            float Aa = AB[k * 128 + ww], Uu = UB[k * 128 + ww];
            UB[k * 128 + ww] = s;
            s = Aa * s + Uu;
        }
    }
    __syncthreads();

    // ---- phase 1c: apply prefixes; y = silu(loc + 0.5*g*(wsum + hsum)); in place ----
    float sf = UF[ck * 128 + w];
    float sfa[16];
#pragma unroll
    for (int i = 0; i < 16; ++i) { sf = av[i] * sf + uv[i]; sfa[i] = sf; }
    float sb = UB[ck * 128 + w];
#pragma unroll
    for (int i = 15; i >= 0; --i) {
        sb = av[i] * sb + uv[i];
        size_t off = pb + (size_t)(h0 + i) * W + w;
        float g = bf2f(G_[off]);
        float v = bf2f(LY[off]) + 0.5f * g * (Sl[(h0 + i) * W + w] + sfa[i] + sb);
        LY[off] = f2bf(v / (1.f + __expf(-v)));
    }
}

extern "C" void kernel_launch(void* const* d_in, const int* in_sizes, int n_in,
                              void* d_out, int out_size, void* d_ws, size_t ws_size,
                              hipStream_t stream) {
    const float* x     = (const float*)d_in[0];
    const float* ln_w  = (const float*)d_in[1];
    const float* ln_b  = (const float*)d_in[2];
    const float* dw_w  = (const float*)d_in[3];
    const float* loc_w = (const float*)d_in[4];
    const float* loc_b = (const float*)d_in[5];
    const float* par_w = (const float*)d_in[6];
    const float* par_b = (const float*)d_in[7];
    const float* out_w = (const float*)d_in[8];
    const float* out_b = (const float*)d_in[9];
    float* out = (float*)d_out;
    unsigned short* wsu = (unsigned short*)d_ws;

    // ws (bf16 units): WB(184320) | A | U | G | ZT(->LOC->Y) | DT, each nb*CHW
    const int WBN = 5 * C * K;                 // 184320
    int nb = 8;
    while (nb > 1) {
        size_t need = (size_t)WBN * 2 + (size_t)5 * nb * CHW * 2;
        if (need <= ws_size) break;
        nb >>= 1;
    }

    prepack_kernel<<<(WBN + 255) / 256, 256, 0, stream>>>(par_w, loc_w, out_w, wsu);

    for (int b0 = 0; b0 < B; b0 += nb) {
        size_t ge = (size_t)nb * CHW;
        unsigned short* WB = wsu;
        unsigned short* Ab = wsu + WBN;
        unsigned short* Ub = Ab + ge;
        unsigned short* Gb = Ub + ge;
        unsigned short* ZT = Gb + ge;          // LN out; later LOC (bf16 NCHW), then Y
        unsigned short* DT = ZT + ge;
        const float* xg = x + (size_t)b0 * CHW;
        int npg = nb * HW;

        // 1. LayerNorm -> ZT [p][K]
        ln_kernel<<<npg / 256, 256, 0, stream>>>(xg, ln_w, ln_b, ZT);
        // 2. gates (3 gy in one kernel) -> A, U, G (bf16 NCHW)
        conv_mfma_kernel<0><<<npg / 256, 256, 73728, stream>>>(
            ZT, nullptr, WB, par_b, nullptr, nullptr, Ab, Ub, Gb);
        // 3. depthwise 3x3 -> DT [p][K]  (LDS-tiled, coalesced)
        dw3x3_kernel<<<nb * 128, 256, 0, stream>>>(ZT, dw_w, DT);
        // 4. local conv -> LOC (bf16 NCHW) overwriting ZT (now dead)
        conv_mfma_kernel<1><<<npg / 256, 256, 73728, stream>>>(
            DT, nullptr, WB + 3 * C * K, loc_b, nullptr, nullptr, ZT, nullptr, nullptr);
        // 5. fused scans + loc add + silu, in place -> Y (= ZT buffer)
        scan_fused_kernel<<<nb * C, 1024, (HW + 4096) * 4, stream>>>(Ab, Ub, Gb, ZT);
        // 6. out conv (reads Y bf16) + bias + residual -> d_out
        conv_mfma_kernel<2><<<npg / 256, 256, 73728, stream>>>(
            nullptr, ZT, WB + 4 * C * K, out_b, xg, out + (size_t)b0 * CHW,
            nullptr, nullptr, nullptr);
    }
}